// Round 2
// baseline (485.546 us; speedup 1.0000x reference)
//
#include <hip/hip_runtime.h>

#define HID   64
#define ENC_T 20
#define DEC_T 30
#define HS    72   // sH row stride in bf16 elements: 144B, 16B-aligned, bank-staggered

typedef __bf16 bf16x8 __attribute__((ext_vector_type(8)));
typedef float  f32x4  __attribute__((ext_vector_type(4)));
typedef unsigned short u16x8 __attribute__((ext_vector_type(8)));
typedef unsigned short ushort_t;
typedef unsigned int   uint_t;

#if __has_builtin(__builtin_amdgcn_exp2f)
#define EXP2F(x) __builtin_amdgcn_exp2f(x)
#else
#define EXP2F(x) exp2f(x)
#endif
#if __has_builtin(__builtin_amdgcn_rcpf)
#define RCPF(x) __builtin_amdgcn_rcpf(x)
#else
#define RCPF(x) (1.0f / (x))
#endif

__device__ __forceinline__ float bf2f(ushort_t u) {
    union { uint_t i; float f; } v; v.i = ((uint_t)u) << 16; return v.f;
}
__device__ __forceinline__ ushort_t f2bf(float f) {
    union { float f; uint_t i; } v; v.f = f;
    uint_t i = v.i;
    return (ushort_t)((i + 0x7FFFu + ((i >> 16) & 1u)) >> 16);  // RNE
}
__device__ __forceinline__ float fsig(float x) {
    float e = EXP2F(x * -1.4426950408889634f);
    return RCPF(1.0f + e);
}
__device__ __forceinline__ float ftanh_(float x) {
    float e = EXP2F(x * -2.8853900817779268f);
    return 2.0f * RCPF(1.0f + e) - 1.0f;
}

struct bfpair { bf16x8 hi, lo; };

// Split 8 consecutive fp32 into bf16 hi + lo fragments (x ~= hi + lo to ~16 bits)
__device__ __forceinline__ bfpair split8(const float* __restrict__ p) {
    f32x4 f0 = *(const f32x4*)p;
    f32x4 f1 = *(const f32x4*)(p + 4);
    u16x8 h, l;
    #pragma unroll
    for (int u = 0; u < 4; ++u) {
        ushort_t a = f2bf(f0[u]); h[u]     = a; l[u]     = f2bf(f0[u] - bf2f(a));
        ushort_t b = f2bf(f1[u]); h[u + 4] = b; l[u + 4] = f2bf(f1[u] - bf2f(b));
    }
    bfpair r;
    __builtin_memcpy(&r.hi, &h, 16);
    __builtin_memcpy(&r.lo, &l, 16);
    return r;
}

__global__ __launch_bounds__(256, 3)
void lstm_seq2seq(const float* __restrict__ traj,
                  const float* __restrict__ WihE, const float* __restrict__ WhhE,
                  const float* __restrict__ bihE, const float* __restrict__ bhhE,
                  const float* __restrict__ WihD, const float* __restrict__ WhhD,
                  const float* __restrict__ bihD, const float* __restrict__ bhhD,
                  const float* __restrict__ Wpos, const float* __restrict__ bpos,
                  float* __restrict__ out)
{
    __shared__ __align__(16) ushort_t sHh[2][16 * HS];  // h hi, double buffer
    __shared__ __align__(16) ushort_t sHl[2][16 * HS];  // h lo
    __shared__ __align__(16) float    sX[16 * ENC_T * 2];  // traj tile fp32

    const int tid  = threadIdx.x;
    const int w    = tid >> 6;      // wave 0..3 -> gate-unit tile (units 16w..16w+15)
    const int lane = tid & 63;
    const int col  = lane & 15;     // MFMA col (n for B / C; m for A)
    const int quad = lane >> 4;
    const int wg   = blockIdx.x;    // 16 batch rows per workgroup

    // ---- stage trajectory tile: rows 16wg..16wg+15 = 640 contiguous floats ----
    {
        const float* src = traj + (size_t)wg * (16 * ENC_T * 2);
        #pragma unroll
        for (int i = 0; i < 3; ++i) {
            int idx = tid + i * 256;
            if (idx < 640) sX[idx] = src[idx];
        }
    }
    // ---- zero h buffer 0 ----
    {
        uint_t* hz0 = (uint_t*)&sHh[0][0];
        uint_t* hz1 = (uint_t*)&sHl[0][0];
        for (int j = tid; j < 16 * HS / 2; j += 256) { hz0[j] = 0; hz1[j] = 0; }
    }

    // ---- per-lane encoder constants (fp32, exact): gate g = 64j + 16w + col ----
    float wi0[4], wi1[4], bE[4];
    #pragma unroll
    for (int j = 0; j < 4; ++j) {
        int g = 64 * j + 16 * w + col;
        wi0[j] = WihE[g * 2 + 0];
        wi1[j] = WihE[g * 2 + 1];
        bE[j]  = bihE[g] + bhhE[g];
    }

    // ---- encoder W_hh fragments direct from global -> registers (hi/lo) ----
    // B-frag layout: B[n = col][k = kb*32 + quad*8 + u], W row-major [256][64]
    bfpair bw[4][2];
    #pragma unroll
    for (int j = 0; j < 4; ++j) {
        int g = 64 * j + 16 * w + col;
        #pragma unroll
        for (int kb = 0; kb < 2; ++kb)
            bw[j][kb] = split8(WhhE + g * 64 + kb * 32 + quad * 8);
    }

    float c[4] = {0.f, 0.f, 0.f, 0.f};   // c-state rows quad*4+r, unit 16w+col
    int buf = 0;

    __syncthreads();

    // =========================== ENCODER ===========================
    for (int t = 0; t < ENC_T; ++t) {
        f32x4 acc[4];
        #pragma unroll
        for (int r = 0; r < 4; ++r) {
            float x0 = sX[(quad * 4 + r) * (ENC_T * 2) + 2 * t + 0];
            float x1 = sX[(quad * 4 + r) * (ENC_T * 2) + 2 * t + 1];
            #pragma unroll
            for (int j = 0; j < 4; ++j)
                acc[j][r] = fmaf(wi1[j], x1, fmaf(wi0[j], x0, bE[j]));
        }
        bf16x8 a0h = *(const bf16x8*)&sHh[buf][col * HS +  0 + quad * 8];
        bf16x8 a1h = *(const bf16x8*)&sHh[buf][col * HS + 32 + quad * 8];
        bf16x8 a0l = *(const bf16x8*)&sHl[buf][col * HS +  0 + quad * 8];
        bf16x8 a1l = *(const bf16x8*)&sHl[buf][col * HS + 32 + quad * 8];
        #pragma unroll
        for (int j = 0; j < 4; ++j) {
            acc[j] = __builtin_amdgcn_mfma_f32_16x16x32_bf16(a0l, bw[j][0].hi, acc[j], 0, 0, 0);
            acc[j] = __builtin_amdgcn_mfma_f32_16x16x32_bf16(a1l, bw[j][1].hi, acc[j], 0, 0, 0);
            acc[j] = __builtin_amdgcn_mfma_f32_16x16x32_bf16(a0h, bw[j][0].lo, acc[j], 0, 0, 0);
            acc[j] = __builtin_amdgcn_mfma_f32_16x16x32_bf16(a1h, bw[j][1].lo, acc[j], 0, 0, 0);
            acc[j] = __builtin_amdgcn_mfma_f32_16x16x32_bf16(a0h, bw[j][0].hi, acc[j], 0, 0, 0);
            acc[j] = __builtin_amdgcn_mfma_f32_16x16x32_bf16(a1h, bw[j][1].hi, acc[j], 0, 0, 0);
        }
        #pragma unroll
        for (int r = 0; r < 4; ++r) {
            float ig = fsig(acc[0][r]);
            float fg = fsig(acc[1][r]);
            float gg = ftanh_(acc[2][r]);
            float og = fsig(acc[3][r]);
            float cn = fmaf(fg, c[r], ig * gg);
            c[r] = cn;
            float hn = og * ftanh_(cn);
            int idx = (quad * 4 + r) * HS + 16 * w + col;
            ushort_t hh = f2bf(hn);
            sHh[buf ^ 1][idx] = hh;
            sHl[buf ^ 1][idx] = f2bf(hn - bf2f(hh));
        }
        __syncthreads();
        buf ^= 1;
    }

    // ---- decoder combined weights Wc = W_ih_dec + W_hh_dec (fp32 add, hi/lo split) ----
    float bD[4];
    #pragma unroll
    for (int j = 0; j < 4; ++j) {
        int g = 64 * j + 16 * w + col;
        bD[j] = bihD[g] + bhhD[g];
        #pragma unroll
        for (int kb = 0; kb < 2; ++kb) {
            int off = g * 64 + kb * 32 + quad * 8;
            float tmp[8];
            #pragma unroll
            for (int u = 0; u < 8; ++u) tmp[u] = WihD[off + u] + WhhD[off + u];
            bw[j][kb] = split8(tmp);
        }
    }

    // projection constants: lane = quad*16 + pcomp*8 + pseg ; row = 4w + quad
    const int prow  = 4 * w + quad;
    const int pcomp = (lane >> 3) & 1;
    const int pseg  = lane & 7;
    float wp[8];
    #pragma unroll
    for (int u = 0; u < 8; ++u) wp[u] = Wpos[pcomp * 64 + pseg * 8 + u];
    const float bp = bpos[pcomp];

    // =========================== DECODER ===========================
    for (int t = 0; t < DEC_T; ++t) {
        f32x4 acc[4];
        #pragma unroll
        for (int j = 0; j < 4; ++j) {
            acc[j][0] = bD[j]; acc[j][1] = bD[j]; acc[j][2] = bD[j]; acc[j][3] = bD[j];
        }
        bf16x8 a0h = *(const bf16x8*)&sHh[buf][col * HS +  0 + quad * 8];
        bf16x8 a1h = *(const bf16x8*)&sHh[buf][col * HS + 32 + quad * 8];
        bf16x8 a0l = *(const bf16x8*)&sHl[buf][col * HS +  0 + quad * 8];
        bf16x8 a1l = *(const bf16x8*)&sHl[buf][col * HS + 32 + quad * 8];
        #pragma unroll
        for (int j = 0; j < 4; ++j) {
            acc[j] = __builtin_amdgcn_mfma_f32_16x16x32_bf16(a0l, bw[j][0].hi, acc[j], 0, 0, 0);
            acc[j] = __builtin_amdgcn_mfma_f32_16x16x32_bf16(a1l, bw[j][1].hi, acc[j], 0, 0, 0);
            acc[j] = __builtin_amdgcn_mfma_f32_16x16x32_bf16(a0h, bw[j][0].lo, acc[j], 0, 0, 0);
            acc[j] = __builtin_amdgcn_mfma_f32_16x16x32_bf16(a1h, bw[j][1].lo, acc[j], 0, 0, 0);
            acc[j] = __builtin_amdgcn_mfma_f32_16x16x32_bf16(a0h, bw[j][0].hi, acc[j], 0, 0, 0);
            acc[j] = __builtin_amdgcn_mfma_f32_16x16x32_bf16(a1h, bw[j][1].hi, acc[j], 0, 0, 0);
        }
        #pragma unroll
        for (int r = 0; r < 4; ++r) {
            float ig = fsig(acc[0][r]);
            float fg = fsig(acc[1][r]);
            float gg = ftanh_(acc[2][r]);
            float og = fsig(acc[3][r]);
            float cn = fmaf(fg, c[r], ig * gg);
            c[r] = cn;
            float hn = og * ftanh_(cn);
            int idx = (quad * 4 + r) * HS + 16 * w + col;
            ushort_t hh = f2bf(hn);
            sHh[buf ^ 1][idx] = hh;
            sHl[buf ^ 1][idx] = f2bf(hn - bf2f(hh));
        }
        __syncthreads();
        buf ^= 1;
        // out_t = h_{t+1} @ Wpos^T + b_pos ; h_{t+1} now in sH*[buf].
        // Safe: next iter writes sH*[buf^1]; sH*[buf] is only rewritten after the
        // NEXT barrier, which no wave passes until its projection is done.
        {
            u16x8 hvh = *(const u16x8*)&sHh[buf][prow * HS + pseg * 8];
            u16x8 hvl = *(const u16x8*)&sHl[buf][prow * HS + pseg * 8];
            float p = 0.f;
            #pragma unroll
            for (int u = 0; u < 8; ++u)
                p = fmaf(bf2f(hvh[u]) + bf2f(hvl[u]), wp[u], p);
            p += __shfl_xor(p, 1, 64);
            p += __shfl_xor(p, 2, 64);
            p += __shfl_xor(p, 4, 64);
            if (pseg == 0)
                out[(size_t)(wg * 16 + prow) * (DEC_T * 2) + t * 2 + pcomp] = p + bp;
        }
    }
}

// fp32 overload helper for split8 on a stack array
__device__ __forceinline__ bfpair split8(const float (&a)[8]) { return split8(&a[0]); }

extern "C" void kernel_launch(void* const* d_in, const int* in_sizes, int n_in,
                              void* d_out, int out_size, void* d_ws, size_t ws_size,
                              hipStream_t stream) {
    const float* traj = (const float*)d_in[0];
    const float* WihE = (const float*)d_in[1];
    const float* WhhE = (const float*)d_in[2];
    const float* bihE = (const float*)d_in[3];
    const float* bhhE = (const float*)d_in[4];
    const float* WihD = (const float*)d_in[5];
    const float* WhhD = (const float*)d_in[6];
    const float* bihD = (const float*)d_in[7];
    const float* bhhD = (const float*)d_in[8];
    const float* Wpos = (const float*)d_in[9];
    const float* bpos = (const float*)d_in[10];
    float* out = (float*)d_out;

    const int B = in_sizes[0] / (ENC_T * 2);   // 65536
    const int grid = B / 16;                   // 4096 workgroups, 16 rows each

    lstm_seq2seq<<<grid, 256, 0, stream>>>(traj, WihE, WhhE, bihE, bhhE,
                                           WihD, WhhD, bihD, bhhD, Wpos, bpos, out);
}